// Round 3
// baseline (238.073 us; speedup 1.0000x reference)
//
#include <hip/hip_runtime.h>
#include <math.h>

#define E_DIM 4096
#define H_NUM 32
#define D_DIM 128
#define PAST_K 8191
#define K_TOT 8192

// workspace layout (float offsets) — contiguous zero-init region [0, 8512)
#define WS_QUERY 0        // 4096
#define WS_KV    4096     // 256 (key_new 0:128, value_new 128:256)
#define WS_L     4352     // 32  (per-head sum of exps)
#define WS_ATTN  4416     // 4096 (UNNORMALIZED sum e*v)
#define WS_ZEND  8512

// ---------------------------------------------------------------- init
__global__ void k_init(float* __restrict__ ws, float* __restrict__ out) {
    int i = blockIdx.x * 256 + threadIdx.x;
    if (i < WS_ZEND) ws[i] = 0.f;
    if (i < E_DIM) out[i] = 0.f;
}

// ---------------------------------------------------------------- q + kv matvec (split-K, atomics)
// grid: (5, 128). bx<4 -> q outputs [bx*1024,+1024); bx==4 -> kv (256 outputs). 32 e per by.
__global__ void k_qkv(const float* __restrict__ hs,
                      const float* __restrict__ q_w, const float* __restrict__ q_b,
                      const float* __restrict__ kv_w, const float* __restrict__ kv_b,
                      float* __restrict__ ws) {
    const int t = threadIdx.x;
    const int e0 = blockIdx.y * 32;
    if (blockIdx.x < 4) {
        const int o = blockIdx.x * 1024 + t * 4;
        float ax = 0.f, ay = 0.f, az = 0.f, aw = 0.f;
#pragma unroll
        for (int i = 0; i < 32; ++i) {
            const int e = e0 + i;
            const float x = hs[e];
            const float4 w = *reinterpret_cast<const float4*>(q_w + (size_t)e * E_DIM + o);
            ax += x * w.x; ay += x * w.y; az += x * w.z; aw += x * w.w;
        }
        if (blockIdx.y == 0) {
            const float4 b = *reinterpret_cast<const float4*>(q_b + o);
            ax += b.x; ay += b.y; az += b.z; aw += b.w;
        }
        float* y = ws + WS_QUERY + o;
        atomicAdd(y + 0, ax); atomicAdd(y + 1, ay);
        atomicAdd(y + 2, az); atomicAdd(y + 3, aw);
    } else {
        if (t >= 64) return;
        const int o = t * 4;
        float ax = 0.f, ay = 0.f, az = 0.f, aw = 0.f;
#pragma unroll
        for (int i = 0; i < 32; ++i) {
            const int e = e0 + i;
            const float x = hs[e];
            const float4 w = *reinterpret_cast<const float4*>(kv_w + (size_t)e * 256 + o);
            ax += x * w.x; ay += x * w.y; az += x * w.z; aw += x * w.w;
        }
        if (blockIdx.y == 0) {
            const float4 b = *reinterpret_cast<const float4*>(kv_b + o);
            ax += b.x; ay += b.y; az += b.z; aw += b.w;
        }
        float* y = ws + WS_KV + o;
        atomicAdd(y + 0, ax); atomicAdd(y + 1, ay);
        atomicAdd(y + 2, az); atomicAdd(y + 3, aw);
    }
}

// ---------------------------------------------------------------- fused attention: scores -> exp -> PV (unnormalized)
// grid: (64, 4) = 256 blocks. 128 k per bx, 8 heads per by. 256 threads.
// Phase A: 2 d-teams x 128 k-lanes -> s[h][k]; exp; partial l atomics.
// Phase B: 8 k-groups x 32 d-quads -> o_unnorm atomics into WS_ATTN.
__global__ void k_attn(const float* __restrict__ past_key,
                       const float* __restrict__ past_value,
                       const float* __restrict__ mask,
                       float* __restrict__ ws,
                       float* __restrict__ out) {
    __shared__ float sq[8 * 128];            // q tile, 4 KB
    __shared__ float sp[8 * 128];            // unnormalized probs, 4 KB
    __shared__ float red[8 * 8 * 32 * 4];    // 32 KB; first 1 KB reused as phase-A partial
    const int t = threadIdx.x;
    const int h0 = blockIdx.y * 8;
    const int k0 = blockIdx.x * 128;
    const float* __restrict__ kvn = ws + WS_KV;

    // stage q[h0..h0+8][0..128] into LDS
#pragma unroll
    for (int i = 0; i < 4; ++i) sq[i * 256 + t] = ws[WS_QUERY + h0 * D_DIM + i * 256 + t];
    __syncthreads();

    // ---- Phase A: scores for 128 k, split over 2 d-teams
    const int team = __builtin_amdgcn_readfirstlane((t >> 7) & 1);
    const int kl = t & 127;
    const int k = k0 + kl;
    const int d0 = team * 64;
    const bool tailA = (k == PAST_K);                     // per-thread loop-invariant
    const float* kp = tailA ? (kvn + d0) : (past_key + (size_t)d0 * PAST_K + k);
    const size_t kstride = tailA ? 1 : PAST_K;

    float acc[8];
#pragma unroll
    for (int h = 0; h < 8; ++h) acc[h] = 0.f;

#pragma unroll 4
    for (int i = 0; i < 64; i += 4) {
        const float kv0 = kp[0];
        const float kv1 = kp[kstride];
        const float kv2 = kp[2 * kstride];
        const float kv3 = kp[3 * kstride];
        kp += 4 * kstride;
#pragma unroll
        for (int h = 0; h < 8; ++h) {
            const float4 qv = *reinterpret_cast<const float4*>(&sq[h * 128 + d0 + i]);
            acc[h] += qv.x * kv0 + qv.y * kv1 + qv.z * kv2 + qv.w * kv3;
        }
    }

    float* part = red;  // alias first 4 KB of red
    if (team == 1) {
#pragma unroll
        for (int h = 0; h < 8; ++h) part[h * 128 + kl] = acc[h];
    }
    __syncthreads();
    if (team == 0) {
        const float scale = 0.08838834764831845f;  // 1/sqrt(128)
        const float mk = mask[k];
#pragma unroll
        for (int h = 0; h < 8; ++h) {
            const float s = acc[h] + part[h * 128 + kl];
            const float e = __expf(s * scale + mk);
            sp[h * 128 + kl] = e;
            float lsum = e;
#pragma unroll
            for (int off = 32; off > 0; off >>= 1) lsum += __shfl_xor(lsum, off);
            if ((t & 63) == 0) atomicAdd(ws + WS_L + h0 + h, lsum);
        }
    }
    __syncthreads();

    // ---- Phase B: o_unnorm += e * V, 8 k-groups x 32 d-quads
    const int kg = t >> 5;
    const int dq = t & 31;
    const int d4 = dq * 4;
    const float* __restrict__ vnew = kvn + D_DIM;

    float4 vacc[8];
#pragma unroll
    for (int h = 0; h < 8; ++h) vacc[h] = make_float4(0.f, 0.f, 0.f, 0.f);

#pragma unroll 4
    for (int kk = 0; kk < 16; ++kk) {
        const int k2 = k0 + kg * 16 + kk;
        const float* vp = (k2 < PAST_K) ? (past_value + (size_t)k2 * D_DIM + d4)
                                        : (vnew + d4);   // branchless address select
        const float4 v = *reinterpret_cast<const float4*>(vp);
#pragma unroll
        for (int h = 0; h < 8; ++h) {
            const float p = sp[h * 128 + kg * 16 + kk];
            vacc[h].x += p * v.x; vacc[h].y += p * v.y;
            vacc[h].z += p * v.z; vacc[h].w += p * v.w;
        }
    }
#pragma unroll
    for (int h = 0; h < 8; ++h)
        *reinterpret_cast<float4*>(&red[((kg * 8 + h) * 32 + dq) * 4]) = vacc[h];
    __syncthreads();

    const int hh = t >> 5;
    float4 s = make_float4(0.f, 0.f, 0.f, 0.f);
#pragma unroll
    for (int gg = 0; gg < 8; ++gg) {
        const float4 r = *reinterpret_cast<const float4*>(&red[((gg * 8 + hh) * 32 + dq) * 4]);
        s.x += r.x; s.y += r.y; s.z += r.z; s.w += r.w;
    }
    float* a = ws + WS_ATTN + (h0 + hh) * D_DIM + d4;
    atomicAdd(a + 0, s.x); atomicAdd(a + 1, s.y);
    atomicAdd(a + 2, s.z); atomicAdd(a + 3, s.w);

    // emit key_perm (out[4096:4224]) and value_new (out[4224:4352]) once
    if (blockIdx.x == 0 && blockIdx.y == 0) out[E_DIM + t] = kvn[t];
}

// ---------------------------------------------------------------- out_proj matvec (split-K, atomics)
// grid: (4, 128). Normalization 1/l[h] folded into the uniform x prologue.
__global__ void k_proj(const float* __restrict__ proj_w, const float* __restrict__ proj_b,
                       const float* __restrict__ ws, float* __restrict__ out) {
    const int t = threadIdx.x;
    const int o = blockIdx.x * 1024 + t * 4;
    const int e0 = blockIdx.y * 32;
    float ax = 0.f, ay = 0.f, az = 0.f, aw = 0.f;
#pragma unroll
    for (int i = 0; i < 32; ++i) {
        const int e = e0 + i;
        const float x = ws[WS_ATTN + e] / ws[WS_L + (e >> 7)];  // wave-uniform scalar
        const float4 w = *reinterpret_cast<const float4*>(proj_w + (size_t)e * E_DIM + o);
        ax += x * w.x; ay += x * w.y; az += x * w.z; aw += x * w.w;
    }
    if (blockIdx.y == 0) {
        const float4 b = *reinterpret_cast<const float4*>(proj_b + o);
        ax += b.x; ay += b.y; az += b.z; aw += b.w;
    }
    atomicAdd(out + o + 0, ax); atomicAdd(out + o + 1, ay);
    atomicAdd(out + o + 2, az); atomicAdd(out + o + 3, aw);
}

extern "C" void kernel_launch(void* const* d_in, const int* in_sizes, int n_in,
                              void* d_out, int out_size, void* d_ws, size_t ws_size,
                              hipStream_t stream) {
    const float* hs      = (const float*)d_in[0];
    const float* past_k  = (const float*)d_in[1];
    const float* past_v  = (const float*)d_in[2];
    const float* mask    = (const float*)d_in[3];
    const float* q_w     = (const float*)d_in[4];
    const float* q_b     = (const float*)d_in[5];
    const float* kv_w    = (const float*)d_in[6];
    const float* kv_b    = (const float*)d_in[7];
    const float* proj_w  = (const float*)d_in[8];
    const float* proj_b  = (const float*)d_in[9];
    float* out = (float*)d_out;
    float* ws  = (float*)d_ws;

    k_init<<<dim3(34),     dim3(256), 0, stream>>>(ws, out);
    k_qkv <<<dim3(5, 128), dim3(256), 0, stream>>>(hs, q_w, q_b, kv_w, kv_b, ws);
    k_attn<<<dim3(64, 4),  dim3(256), 0, stream>>>(past_k, past_v, mask, ws, out);
    k_proj<<<dim3(4, 128), dim3(256), 0, stream>>>(proj_w, proj_b, ws, out);
}

// Round 4
// 236.792 us; speedup vs baseline: 1.0054x; 1.0054x over previous
//
#include <hip/hip_runtime.h>
#include <math.h>

#define E_DIM 4096
#define H_NUM 32
#define D_DIM 128
#define PAST_K 8191
#define K_TOT 8192

// workspace layout (float offsets) — contiguous zero-init region [0, 8512)
#define WS_QUERY 0        // 4096
#define WS_KV    4096     // 256 (key_new 0:128, value_new 128:256)
#define WS_L     4352     // 32  (per-head sum of exps)
#define WS_ATTN  4416     // 4096 (UNNORMALIZED sum e*v)
#define WS_ZEND  8512

// ---------------------------------------------------------------- init
__global__ void k_init(float* __restrict__ ws, float* __restrict__ out) {
    int i = blockIdx.x * 256 + threadIdx.x;
    if (i < WS_ZEND) ws[i] = 0.f;
    if (i < E_DIM) out[i] = 0.f;
}

// ---------------------------------------------------------------- q + kv matvec (split-K, atomics)
// grid: (5, 128). bx<4 -> q outputs [bx*1024,+1024); bx==4 -> kv (256 outputs). 32 e per by.
__global__ void k_qkv(const float* __restrict__ hs,
                      const float* __restrict__ q_w, const float* __restrict__ q_b,
                      const float* __restrict__ kv_w, const float* __restrict__ kv_b,
                      float* __restrict__ ws) {
    const int t = threadIdx.x;
    const int e0 = blockIdx.y * 32;
    if (blockIdx.x < 4) {
        const int o = blockIdx.x * 1024 + t * 4;
        float ax = 0.f, ay = 0.f, az = 0.f, aw = 0.f;
#pragma unroll
        for (int i = 0; i < 32; ++i) {
            const int e = e0 + i;
            const float x = hs[e];
            const float4 w = *reinterpret_cast<const float4*>(q_w + (size_t)e * E_DIM + o);
            ax += x * w.x; ay += x * w.y; az += x * w.z; aw += x * w.w;
        }
        if (blockIdx.y == 0) {
            const float4 b = *reinterpret_cast<const float4*>(q_b + o);
            ax += b.x; ay += b.y; az += b.z; aw += b.w;
        }
        float* y = ws + WS_QUERY + o;
        atomicAdd(y + 0, ax); atomicAdd(y + 1, ay);
        atomicAdd(y + 2, az); atomicAdd(y + 3, aw);
    } else {
        if (t >= 64) return;
        const int o = t * 4;
        float ax = 0.f, ay = 0.f, az = 0.f, aw = 0.f;
#pragma unroll
        for (int i = 0; i < 32; ++i) {
            const int e = e0 + i;
            const float x = hs[e];
            const float4 w = *reinterpret_cast<const float4*>(kv_w + (size_t)e * 256 + o);
            ax += x * w.x; ay += x * w.y; az += x * w.z; aw += x * w.w;
        }
        if (blockIdx.y == 0) {
            const float4 b = *reinterpret_cast<const float4*>(kv_b + o);
            ax += b.x; ay += b.y; az += b.z; aw += b.w;
        }
        float* y = ws + WS_KV + o;
        atomicAdd(y + 0, ax); atomicAdd(y + 1, ay);
        atomicAdd(y + 2, az); atomicAdd(y + 3, aw);
    }
}

// ---------------------------------------------------------------- fused attention: scores -> exp -> PV (unnormalized)
// grid: (64, 8) = 512 blocks, 512 threads (8 waves). 128 k per bx, 4 heads per by.
// Phase A: 4 d-teams(32 d) x 128 k-lanes. Phase B: 4 k-groups(32 k) x 128 d-lanes.
__global__ void __launch_bounds__(512, 4)
k_attn(const float* __restrict__ past_key,
       const float* __restrict__ past_value,
       const float* __restrict__ mask,
       float* __restrict__ ws,
       float* __restrict__ out) {
    __shared__ float sq[4 * 128];     // q tile, 2 KB
    __shared__ float sp[4 * 128];     // unnormalized probs, 2 KB
    __shared__ float red[16 * 128];   // 8 KB (A: parts[team][h][k] teams 1-3; B: red[kg][h][d])
    const int t = threadIdx.x;
    const int h0 = blockIdx.y * 4;
    const int k0 = blockIdx.x * 128;
    const float* __restrict__ kvn = ws + WS_KV;

    // stage q[h0..h0+4][0..128] into LDS
    sq[t] = ws[WS_QUERY + h0 * D_DIM + t];
    __syncthreads();

    // ---- Phase A: scores, 128 k-lanes x 4 d-teams
    const int kl = t & 127;
    const int team = t >> 7;                 // wave-uniform
    const int d0 = team * 32;
    const int k = k0 + kl;
    const bool tailA = (k == PAST_K);        // one lane in one block
    const float* kp = tailA ? (kvn + d0) : (past_key + (size_t)d0 * PAST_K + k);
    const size_t kstr = tailA ? 1 : PAST_K;

    float a0 = 0.f, a1 = 0.f, a2 = 0.f, a3 = 0.f;
#pragma unroll
    for (int i = 0; i < 32; i += 4) {
        const float v0 = kp[0];
        const float v1 = kp[kstr];
        const float v2 = kp[2 * kstr];
        const float v3 = kp[3 * kstr];
        kp += 4 * kstr;
        const float4 q0 = *reinterpret_cast<const float4*>(&sq[0 * 128 + d0 + i]);
        const float4 q1 = *reinterpret_cast<const float4*>(&sq[1 * 128 + d0 + i]);
        const float4 q2 = *reinterpret_cast<const float4*>(&sq[2 * 128 + d0 + i]);
        const float4 q3 = *reinterpret_cast<const float4*>(&sq[3 * 128 + d0 + i]);
        a0 += q0.x * v0 + q0.y * v1 + q0.z * v2 + q0.w * v3;
        a1 += q1.x * v0 + q1.y * v1 + q1.z * v2 + q1.w * v3;
        a2 += q2.x * v0 + q2.y * v1 + q2.z * v2 + q2.w * v3;
        a3 += q3.x * v0 + q3.y * v1 + q3.z * v2 + q3.w * v3;
    }
    if (team != 0) {
        red[(team * 4 + 0) * 128 + kl] = a0;
        red[(team * 4 + 1) * 128 + kl] = a1;
        red[(team * 4 + 2) * 128 + kl] = a2;
        red[(team * 4 + 3) * 128 + kl] = a3;
    }
    __syncthreads();
    if (team == 0) {
        const float scale = 0.08838834764831845f;  // 1/sqrt(128)
        const float mk = mask[k];
        float s0 = a0, s1 = a1, s2 = a2, s3 = a3;
#pragma unroll
        for (int tm = 1; tm < 4; ++tm) {
            s0 += red[(tm * 4 + 0) * 128 + kl];
            s1 += red[(tm * 4 + 1) * 128 + kl];
            s2 += red[(tm * 4 + 2) * 128 + kl];
            s3 += red[(tm * 4 + 3) * 128 + kl];
        }
        const float e0 = __expf(s0 * scale + mk);
        const float e1 = __expf(s1 * scale + mk);
        const float e2 = __expf(s2 * scale + mk);
        const float e3 = __expf(s3 * scale + mk);
        sp[0 * 128 + kl] = e0;
        sp[1 * 128 + kl] = e1;
        sp[2 * 128 + kl] = e2;
        sp[3 * 128 + kl] = e3;
        float l0 = e0, l1 = e1, l2 = e2, l3 = e3;
#pragma unroll
        for (int off = 32; off > 0; off >>= 1) {
            l0 += __shfl_xor(l0, off);
            l1 += __shfl_xor(l1, off);
            l2 += __shfl_xor(l2, off);
            l3 += __shfl_xor(l3, off);
        }
        if ((t & 63) == 0) {
            atomicAdd(ws + WS_L + h0 + 0, l0);
            atomicAdd(ws + WS_L + h0 + 1, l1);
            atomicAdd(ws + WS_L + h0 + 2, l2);
            atomicAdd(ws + WS_L + h0 + 3, l3);
        }
    }
    __syncthreads();

    // ---- Phase B: o_unnorm += e * V, 4 k-groups(32 k) x 128 d-lanes
    const int d = t & 127;
    const int kg = t >> 7;                   // wave-uniform
    const int kb = k0 + kg * 32;
    const float* __restrict__ vp = past_value + (size_t)kb * D_DIM + d;
    // only global k = 8191 (bx=63, kg=3, kk=31) is the new token — hoisted out of loop
    const float* __restrict__ vlast =
        (kb + 31 == PAST_K) ? (kvn + D_DIM + d) : (vp + 31 * (size_t)D_DIM);

    float b0 = 0.f, b1 = 0.f, b2 = 0.f, b3 = 0.f;
#pragma unroll
    for (int kk = 0; kk < 31; ++kk) {
        const float v = vp[(size_t)kk * D_DIM];
        const float p0 = sp[0 * 128 + kg * 32 + kk];  // wave-uniform -> broadcast
        const float p1 = sp[1 * 128 + kg * 32 + kk];
        const float p2 = sp[2 * 128 + kg * 32 + kk];
        const float p3 = sp[3 * 128 + kg * 32 + kk];
        b0 += p0 * v; b1 += p1 * v; b2 += p2 * v; b3 += p3 * v;
    }
    {
        const float v = *vlast;
        b0 += sp[0 * 128 + kg * 32 + 31] * v;
        b1 += sp[1 * 128 + kg * 32 + 31] * v;
        b2 += sp[2 * 128 + kg * 32 + 31] * v;
        b3 += sp[3 * 128 + kg * 32 + 31] * v;
    }
    __syncthreads();   // red reuse: phase-A readers are done
    red[(kg * 4 + 0) * 128 + d] = b0;
    red[(kg * 4 + 1) * 128 + d] = b1;
    red[(kg * 4 + 2) * 128 + d] = b2;
    red[(kg * 4 + 3) * 128 + d] = b3;
    __syncthreads();

    // reduce over 4 k-groups: thread t -> (h = t>>7, d = t&127); one atomic per (h,d)
    const int hh = t >> 7;
    float s = red[(0 * 4 + hh) * 128 + d] + red[(1 * 4 + hh) * 128 + d] +
              red[(2 * 4 + hh) * 128 + d] + red[(3 * 4 + hh) * 128 + d];
    atomicAdd(ws + WS_ATTN + (h0 + hh) * D_DIM + d, s);

    // emit key_perm (out[4096:4224]) and value_new (out[4224:4352]) once
    if (blockIdx.x == 0 && blockIdx.y == 0 && t < 256) out[E_DIM + t] = kvn[t];
}

// ---------------------------------------------------------------- out_proj matvec (split-K, atomics)
// grid: (4, 128). Normalization 1/l[h] folded into the uniform x prologue.
__global__ void k_proj(const float* __restrict__ proj_w, const float* __restrict__ proj_b,
                       const float* __restrict__ ws, float* __restrict__ out) {
    const int t = threadIdx.x;
    const int o = blockIdx.x * 1024 + t * 4;
    const int e0 = blockIdx.y * 32;
    float ax = 0.f, ay = 0.f, az = 0.f, aw = 0.f;
#pragma unroll
    for (int i = 0; i < 32; ++i) {
        const int e = e0 + i;
        const float x = ws[WS_ATTN + e] / ws[WS_L + (e >> 7)];  // wave-uniform scalar
        const float4 w = *reinterpret_cast<const float4*>(proj_w + (size_t)e * E_DIM + o);
        ax += x * w.x; ay += x * w.y; az += x * w.z; aw += x * w.w;
    }
    if (blockIdx.y == 0) {
        const float4 b = *reinterpret_cast<const float4*>(proj_b + o);
        ax += b.x; ay += b.y; az += b.z; aw += b.w;
    }
    atomicAdd(out + o + 0, ax); atomicAdd(out + o + 1, ay);
    atomicAdd(out + o + 2, az); atomicAdd(out + o + 3, aw);
}

extern "C" void kernel_launch(void* const* d_in, const int* in_sizes, int n_in,
                              void* d_out, int out_size, void* d_ws, size_t ws_size,
                              hipStream_t stream) {
    const float* hs      = (const float*)d_in[0];
    const float* past_k  = (const float*)d_in[1];
    const float* past_v  = (const float*)d_in[2];
    const float* mask    = (const float*)d_in[3];
    const float* q_w     = (const float*)d_in[4];
    const float* q_b     = (const float*)d_in[5];
    const float* kv_w    = (const float*)d_in[6];
    const float* kv_b    = (const float*)d_in[7];
    const float* proj_w  = (const float*)d_in[8];
    const float* proj_b  = (const float*)d_in[9];
    float* out = (float*)d_out;
    float* ws  = (float*)d_ws;

    k_init<<<dim3(34),     dim3(256), 0, stream>>>(ws, out);
    k_qkv <<<dim3(5, 128), dim3(256), 0, stream>>>(hs, q_w, q_b, kv_w, kv_b, ws);
    k_attn<<<dim3(64, 8),  dim3(512), 0, stream>>>(past_k, past_v, mask, ws, out);
    k_proj<<<dim3(4, 128), dim3(256), 0, stream>>>(proj_w, proj_b, ws, out);
}

// Round 5
// 213.364 us; speedup vs baseline: 1.1158x; 1.1098x over previous
//
#include <hip/hip_runtime.h>
#include <math.h>

#define E_DIM 4096
#define H_NUM 32
#define D_DIM 128
#define PAST_K 8191
#define K_TOT 8192

// workspace layout (float offsets)
#define WS_QUERY 0                    // 4096
#define WS_KV    4096                 // 256 (key_new 0:128, value_new 128:256)
#define WS_L     4352                 // 32  (per-head sum of exps)
#define WS_ATTN  4416                 // 4096 (UNNORMALIZED sum e*v)
#define WS_PQ    8512                 // qkv partials: 128 splits x 4352
#define WS_PA    (WS_PQ + 128*4352)   // attn partials: 64 kx x 4096
#define WS_PL    (WS_PA + 64*4096)    // l partials: 64 kx x 8 hy x 8
#define WS_PP    (WS_PL + 4096)       // proj partials: 128 splits x 4096

// ---------------------------------------------------------------- q + kv matvec (split-K, partial stores)
// grid: (5, 128). bx<4 -> q outputs [bx*1024,+1024); bx==4 -> kv (256 outputs). 32 e per by.
__global__ void k_qkv(const float* __restrict__ hs,
                      const float* __restrict__ q_w,
                      const float* __restrict__ kv_w,
                      float* __restrict__ ws) {
    const int t = threadIdx.x;
    const int e0 = blockIdx.y * 32;
    if (blockIdx.x < 4) {
        const int o = blockIdx.x * 1024 + t * 4;
        float ax = 0.f, ay = 0.f, az = 0.f, aw = 0.f;
#pragma unroll
        for (int i = 0; i < 32; ++i) {
            const int e = e0 + i;
            const float x = hs[e];
            const float4 w = *reinterpret_cast<const float4*>(q_w + (size_t)e * E_DIM + o);
            ax += x * w.x; ay += x * w.y; az += x * w.z; aw += x * w.w;
        }
        *reinterpret_cast<float4*>(ws + WS_PQ + (size_t)blockIdx.y * 4352 + o) =
            make_float4(ax, ay, az, aw);
    } else {
        if (t >= 64) return;
        const int o = t * 4;
        float ax = 0.f, ay = 0.f, az = 0.f, aw = 0.f;
#pragma unroll
        for (int i = 0; i < 32; ++i) {
            const int e = e0 + i;
            const float x = hs[e];
            const float4 w = *reinterpret_cast<const float4*>(kv_w + (size_t)e * 256 + o);
            ax += x * w.x; ay += x * w.y; az += x * w.z; aw += x * w.w;
        }
        *reinterpret_cast<float4*>(ws + WS_PQ + (size_t)blockIdx.y * 4352 + 4096 + o) =
            make_float4(ax, ay, az, aw);
    }
}

// ---------------------------------------------------------------- reduce qkv partials (+bias) -> WS_QUERY / WS_KV
// grid: 17 blocks x 256 threads (4096 q + 256 kv outputs)
__global__ void k_qkv_reduce(const float* __restrict__ q_b, const float* __restrict__ kv_b,
                             float* __restrict__ ws) {
    const int o = blockIdx.x * 256 + threadIdx.x;
    float acc = 0.f;
#pragma unroll 8
    for (int s = 0; s < 128; ++s) acc += ws[WS_PQ + (size_t)s * 4352 + o];
    if (o < 4096) ws[WS_QUERY + o] = acc + q_b[o];
    else          ws[WS_KV + (o - 4096)] = acc + kv_b[o - 4096];
}

// ---------------------------------------------------------------- fused attention: scores -> exp -> PV partials
// grid: (64, 8) = 512 blocks, 512 threads. 128 k per bx, 4 heads per by. NO atomics.
__global__ void __launch_bounds__(512, 4)
k_attn(const float* __restrict__ past_key,
       const float* __restrict__ past_value,
       const float* __restrict__ mask,
       float* __restrict__ ws,
       float* __restrict__ out) {
    __shared__ float sq[4 * 128];     // q tile, 2 KB
    __shared__ float sp[4 * 128];     // unnormalized probs, 2 KB
    __shared__ float red[16 * 128];   // 8 KB
    const int t = threadIdx.x;
    const int hy = blockIdx.y;
    const int kx = blockIdx.x;
    const int h0 = hy * 4;
    const int k0 = kx * 128;
    const float* __restrict__ kvn = ws + WS_KV;

    sq[t % 512] = ws[WS_QUERY + h0 * D_DIM + (t % 512)];
    __syncthreads();

    // ---- Phase A: scores, 128 k-lanes x 4 d-teams(32 d)
    const int kl = t & 127;
    const int team = t >> 7;
    const int d0 = team * 32;
    const int k = k0 + kl;
    const bool tailA = (k == PAST_K);
    const float* kp = tailA ? (kvn + d0) : (past_key + (size_t)d0 * PAST_K + k);
    const size_t kstr = tailA ? 1 : PAST_K;

    float a0 = 0.f, a1 = 0.f, a2 = 0.f, a3 = 0.f;
#pragma unroll
    for (int i = 0; i < 32; i += 4) {
        const float v0 = kp[0];
        const float v1 = kp[kstr];
        const float v2 = kp[2 * kstr];
        const float v3 = kp[3 * kstr];
        kp += 4 * kstr;
        const float4 q0 = *reinterpret_cast<const float4*>(&sq[0 * 128 + d0 + i]);
        const float4 q1 = *reinterpret_cast<const float4*>(&sq[1 * 128 + d0 + i]);
        const float4 q2 = *reinterpret_cast<const float4*>(&sq[2 * 128 + d0 + i]);
        const float4 q3 = *reinterpret_cast<const float4*>(&sq[3 * 128 + d0 + i]);
        a0 += q0.x * v0 + q0.y * v1 + q0.z * v2 + q0.w * v3;
        a1 += q1.x * v0 + q1.y * v1 + q1.z * v2 + q1.w * v3;
        a2 += q2.x * v0 + q2.y * v1 + q2.z * v2 + q2.w * v3;
        a3 += q3.x * v0 + q3.y * v1 + q3.z * v2 + q3.w * v3;
    }
    if (team != 0) {
        red[(team * 4 + 0) * 128 + kl] = a0;
        red[(team * 4 + 1) * 128 + kl] = a1;
        red[(team * 4 + 2) * 128 + kl] = a2;
        red[(team * 4 + 3) * 128 + kl] = a3;
    }
    __syncthreads();
    if (team == 0) {
        const float scale = 0.08838834764831845f;  // 1/sqrt(128)
        const float mk = mask[k];
        float s0 = a0, s1 = a1, s2 = a2, s3 = a3;
#pragma unroll
        for (int tm = 1; tm < 4; ++tm) {
            s0 += red[(tm * 4 + 0) * 128 + kl];
            s1 += red[(tm * 4 + 1) * 128 + kl];
            s2 += red[(tm * 4 + 2) * 128 + kl];
            s3 += red[(tm * 4 + 3) * 128 + kl];
        }
        const float e0 = __expf(s0 * scale + mk);
        const float e1 = __expf(s1 * scale + mk);
        const float e2 = __expf(s2 * scale + mk);
        const float e3 = __expf(s3 * scale + mk);
        sp[0 * 128 + kl] = e0;
        sp[1 * 128 + kl] = e1;
        sp[2 * 128 + kl] = e2;
        sp[3 * 128 + kl] = e3;
        float l0 = e0, l1 = e1, l2 = e2, l3 = e3;
#pragma unroll
        for (int off = 32; off > 0; off >>= 1) {
            l0 += __shfl_xor(l0, off);
            l1 += __shfl_xor(l1, off);
            l2 += __shfl_xor(l2, off);
            l3 += __shfl_xor(l3, off);
        }
        if ((t & 63) == 0) {
            const int w = t >> 6;  // wave 0 or 1
            float* pl = ws + WS_PL + ((size_t)(kx * 8 + hy)) * 8 + w * 4;
            pl[0] = l0; pl[1] = l1; pl[2] = l2; pl[3] = l3;
        }
    }
    __syncthreads();

    // ---- Phase B: partial o += e * V, 4 k-groups(32 k) x 128 d-lanes
    const int d = t & 127;
    const int kg = t >> 7;
    const int kb = k0 + kg * 32;
    const float* __restrict__ vp = past_value + (size_t)kb * D_DIM + d;
    const float* __restrict__ vlast =
        (kb + 31 == PAST_K) ? (kvn + D_DIM + d) : (vp + 31 * (size_t)D_DIM);

    float b0 = 0.f, b1 = 0.f, b2 = 0.f, b3 = 0.f;
#pragma unroll
    for (int kk = 0; kk < 31; ++kk) {
        const float v = vp[(size_t)kk * D_DIM];
        b0 += sp[0 * 128 + kg * 32 + kk] * v;
        b1 += sp[1 * 128 + kg * 32 + kk] * v;
        b2 += sp[2 * 128 + kg * 32 + kk] * v;
        b3 += sp[3 * 128 + kg * 32 + kk] * v;
    }
    {
        const float v = *vlast;
        b0 += sp[0 * 128 + kg * 32 + 31] * v;
        b1 += sp[1 * 128 + kg * 32 + 31] * v;
        b2 += sp[2 * 128 + kg * 32 + 31] * v;
        b3 += sp[3 * 128 + kg * 32 + 31] * v;
    }
    __syncthreads();
    red[(kg * 4 + 0) * 128 + d] = b0;
    red[(kg * 4 + 1) * 128 + d] = b1;
    red[(kg * 4 + 2) * 128 + d] = b2;
    red[(kg * 4 + 3) * 128 + d] = b3;
    __syncthreads();

    const int hh = t >> 7;
    const float s = red[(0 * 4 + hh) * 128 + d] + red[(1 * 4 + hh) * 128 + d] +
                    red[(2 * 4 + hh) * 128 + d] + red[(3 * 4 + hh) * 128 + d];
    ws[WS_PA + (size_t)kx * 4096 + (h0 + hh) * D_DIM + d] = s;  // coalesced store, no atomic

    if (kx == 0 && hy == 0 && t < 256) out[E_DIM + t] = kvn[t];
}

// ---------------------------------------------------------------- reduce attn partials -> WS_ATTN, WS_L
// grid: 17 blocks x 256 threads (blocks 0-15: attn; block 16: l)
__global__ void k_attn_reduce(float* __restrict__ ws) {
    const int t = threadIdx.x;
    if (blockIdx.x < 16) {
        const int o = blockIdx.x * 256 + t;
        float acc = 0.f;
#pragma unroll 8
        for (int s = 0; s < 64; ++s) acc += ws[WS_PA + (size_t)s * 4096 + o];
        ws[WS_ATTN + o] = acc;
    } else if (t < 32) {
        const int hy = t >> 2, hh = t & 3;
        float acc = 0.f;
#pragma unroll 8
        for (int kx = 0; kx < 64; ++kx) {
            const float* pl = ws + WS_PL + ((size_t)(kx * 8 + hy)) * 8;
            acc += pl[hh] + pl[4 + hh];
        }
        ws[WS_L + t] = acc;
    }
}

// ---------------------------------------------------------------- out_proj matvec (split-K, partial stores)
// grid: (4, 128). Normalization 1/l[h] folded into the uniform x prologue.
__global__ void k_proj(const float* __restrict__ proj_w,
                       const float* __restrict__ ws, float* __restrict__ wsp) {
    const int t = threadIdx.x;
    const int o = blockIdx.x * 1024 + t * 4;
    const int e0 = blockIdx.y * 32;
    float ax = 0.f, ay = 0.f, az = 0.f, aw = 0.f;
#pragma unroll
    for (int i = 0; i < 32; ++i) {
        const int e = e0 + i;
        const float x = ws[WS_ATTN + e] / ws[WS_L + (e >> 7)];  // wave-uniform scalar
        const float4 w = *reinterpret_cast<const float4*>(proj_w + (size_t)e * E_DIM + o);
        ax += x * w.x; ay += x * w.y; az += x * w.z; aw += x * w.w;
    }
    *reinterpret_cast<float4*>(wsp + WS_PP + (size_t)blockIdx.y * 4096 + o) =
        make_float4(ax, ay, az, aw);
}

// ---------------------------------------------------------------- reduce proj partials (+bias) -> d_out
// grid: 16 blocks x 256 threads
__global__ void k_proj_reduce(const float* __restrict__ proj_b,
                              float* __restrict__ ws, float* __restrict__ out) {
    const int o = blockIdx.x * 256 + threadIdx.x;
    float acc = proj_b[o];
#pragma unroll 8
    for (int s = 0; s < 128; ++s) acc += ws[WS_PP + (size_t)s * 4096 + o];
    out[o] = acc;
}

extern "C" void kernel_launch(void* const* d_in, const int* in_sizes, int n_in,
                              void* d_out, int out_size, void* d_ws, size_t ws_size,
                              hipStream_t stream) {
    const float* hs      = (const float*)d_in[0];
    const float* past_k  = (const float*)d_in[1];
    const float* past_v  = (const float*)d_in[2];
    const float* mask    = (const float*)d_in[3];
    const float* q_w     = (const float*)d_in[4];
    const float* q_b     = (const float*)d_in[5];
    const float* kv_w    = (const float*)d_in[6];
    const float* kv_b    = (const float*)d_in[7];
    const float* proj_w  = (const float*)d_in[8];
    const float* proj_b  = (const float*)d_in[9];
    float* out = (float*)d_out;
    float* ws  = (float*)d_ws;

    k_qkv        <<<dim3(5, 128), dim3(256), 0, stream>>>(hs, q_w, kv_w, ws);
    k_qkv_reduce <<<dim3(17),     dim3(256), 0, stream>>>(q_b, kv_b, ws);
    k_attn       <<<dim3(64, 8),  dim3(512), 0, stream>>>(past_k, past_v, mask, ws, out);
    k_attn_reduce<<<dim3(17),     dim3(256), 0, stream>>>(ws);
    k_proj       <<<dim3(4, 128), dim3(256), 0, stream>>>(proj_w, ws, ws);
    k_proj_reduce<<<dim3(16),     dim3(256), 0, stream>>>(proj_b, ws, out);
}

// Round 6
// 201.125 us; speedup vs baseline: 1.1837x; 1.0609x over previous
//
#include <hip/hip_runtime.h>
#include <math.h>

#define E_DIM 4096
#define H_NUM 32
#define D_DIM 128
#define PAST_K 8191
#define K_TOT 8192

// workspace layout (float offsets)
#define WS_QUERY 0                       // 4096
#define WS_KV    4096                    // 256 (key_new 0:128, value_new 128:256)
#define WS_PQ    4608                    // qkv partials: 256 splits x 4352
#define WS_PA    (WS_PQ + 256*4352)      // attn partials: 128 kx x 4096
#define WS_PL    (WS_PA + 128*4096)      // l partials: 128 kx x 8 hy x 4
#define WS_PP    (WS_PL + 4096)          // proj partials: 256 splits x 4096

// ---------------------------------------------------------------- q + kv matvec (split-K=256, partial stores)
// grid: (5, 256), 256 thr. bx<4 -> q cols [bx*1024,+1024); bx==4 -> kv (256 outs). 16 rows per by.
__global__ void k_qkv(const float* __restrict__ hs,
                      const float* __restrict__ q_w,
                      const float* __restrict__ kv_w,
                      float* __restrict__ ws) {
    const int t = threadIdx.x;
    const int e0 = blockIdx.y * 16;
    if (blockIdx.x < 4) {
        const int o = blockIdx.x * 1024 + t * 4;
        float ax = 0.f, ay = 0.f, az = 0.f, aw = 0.f;
#pragma unroll
        for (int i = 0; i < 16; ++i) {
            const int e = e0 + i;
            const float x = hs[e];
            const float4 w = *reinterpret_cast<const float4*>(q_w + (size_t)e * E_DIM + o);
            ax += x * w.x; ay += x * w.y; az += x * w.z; aw += x * w.w;
        }
        *reinterpret_cast<float4*>(ws + WS_PQ + (size_t)blockIdx.y * 4352 + o) =
            make_float4(ax, ay, az, aw);
    } else {
        if (t >= 64) return;
        const int o = t * 4;
        float ax = 0.f, ay = 0.f, az = 0.f, aw = 0.f;
#pragma unroll
        for (int i = 0; i < 16; ++i) {
            const int e = e0 + i;
            const float x = hs[e];
            const float4 w = *reinterpret_cast<const float4*>(kv_w + (size_t)e * 256 + o);
            ax += x * w.x; ay += x * w.y; az += x * w.z; aw += x * w.w;
        }
        *reinterpret_cast<float4*>(ws + WS_PQ + (size_t)blockIdx.y * 4352 + 4096 + o) =
            make_float4(ax, ay, az, aw);
    }
}

// ---------------------------------------------------------------- reduce qkv partials (+bias); also emits out[4096:4352]
// grid: 68 blocks x 256 thr. Block: 64 outputs x 4 split-groups(64 splits).
__global__ void k_qkv_reduce(const float* __restrict__ q_b, const float* __restrict__ kv_b,
                             float* __restrict__ ws, float* __restrict__ out) {
    __shared__ float rr[256];
    const int t = threadIdx.x;
    const int ol = t & 63;
    const int sg = t >> 6;
    const int o = blockIdx.x * 64 + ol;
    float acc = 0.f;
#pragma unroll 8
    for (int s = sg * 64; s < sg * 64 + 64; ++s)
        acc += ws[WS_PQ + (size_t)s * 4352 + o];
    rr[sg * 64 + ol] = acc;
    __syncthreads();
    if (t < 64) {
        float v = rr[ol] + rr[64 + ol] + rr[128 + ol] + rr[192 + ol];
        const int oo = blockIdx.x * 64 + ol;
        if (oo < 4096) {
            ws[WS_QUERY + oo] = v + q_b[oo];
        } else {
            const int i = oo - 4096;
            const float r = v + kv_b[i];
            ws[WS_KV + i] = r;
            out[oo] = r;  // key_perm / value_new outputs (out[4096:4352])
        }
    }
}

// ---------------------------------------------------------------- fused attention: scores -> exp -> PV partials
// grid: (128, 8) = 1024 blocks, 512 thr. 64 k per bx, 4 heads per by. No atomics.
// Phase A: 64 k-lanes x 8 d-teams(16 d). Phase B: 128 d-lanes x 4 kg(16 k).
__global__ void __launch_bounds__(512, 4)
k_attn(const float* __restrict__ past_key,
       const float* __restrict__ past_value,
       const float* __restrict__ mask,
       float* __restrict__ ws) {
    __shared__ float sq[4 * 128];     // q tile (4 heads x 128 d), 2 KB
    __shared__ float sp[4 * 64];      // unnormalized probs, 1 KB
    __shared__ float red[2048];       // 8 KB (A: [7 teams][4 h][64 k]; B: [4 kg][4 h][128 d])
    const int t = threadIdx.x;
    const int hy = blockIdx.y;
    const int kx = blockIdx.x;
    const int h0 = hy * 4;
    const int k0 = kx * 64;
    const float* __restrict__ kvn = ws + WS_KV;

    sq[t] = ws[WS_QUERY + h0 * D_DIM + t];
    __syncthreads();

    // ---- Phase A
    const int kl = t & 63;
    const int team = t >> 6;
    const int d0 = team * 16;
    const int k = k0 + kl;
    const bool tailA = (k == PAST_K);
    const float* kp = tailA ? (kvn + d0) : (past_key + (size_t)d0 * PAST_K + k);
    const size_t kstr = tailA ? 1 : PAST_K;

    float a0 = 0.f, a1 = 0.f, a2 = 0.f, a3 = 0.f;
#pragma unroll
    for (int i = 0; i < 16; i += 4) {
        const float v0 = kp[0];
        const float v1 = kp[kstr];
        const float v2 = kp[2 * kstr];
        const float v3 = kp[3 * kstr];
        kp += 4 * kstr;
        const float4 q0 = *reinterpret_cast<const float4*>(&sq[0 * 128 + d0 + i]);
        const float4 q1 = *reinterpret_cast<const float4*>(&sq[1 * 128 + d0 + i]);
        const float4 q2 = *reinterpret_cast<const float4*>(&sq[2 * 128 + d0 + i]);
        const float4 q3 = *reinterpret_cast<const float4*>(&sq[3 * 128 + d0 + i]);
        a0 += q0.x * v0 + q0.y * v1 + q0.z * v2 + q0.w * v3;
        a1 += q1.x * v0 + q1.y * v1 + q1.z * v2 + q1.w * v3;
        a2 += q2.x * v0 + q2.y * v1 + q2.z * v2 + q2.w * v3;
        a3 += q3.x * v0 + q3.y * v1 + q3.z * v2 + q3.w * v3;
    }
    if (team != 0) {
        red[((team - 1) * 4 + 0) * 64 + kl] = a0;
        red[((team - 1) * 4 + 1) * 64 + kl] = a1;
        red[((team - 1) * 4 + 2) * 64 + kl] = a2;
        red[((team - 1) * 4 + 3) * 64 + kl] = a3;
    }
    __syncthreads();
    if (team == 0) {   // one full wave: lanes 0..63 = kl
        const float scale = 0.08838834764831845f;  // 1/sqrt(128)
        const float mk = mask[k];
        float s0 = a0, s1 = a1, s2 = a2, s3 = a3;
#pragma unroll
        for (int tm = 0; tm < 7; ++tm) {
            s0 += red[(tm * 4 + 0) * 64 + kl];
            s1 += red[(tm * 4 + 1) * 64 + kl];
            s2 += red[(tm * 4 + 2) * 64 + kl];
            s3 += red[(tm * 4 + 3) * 64 + kl];
        }
        const float e0 = __expf(s0 * scale + mk);
        const float e1 = __expf(s1 * scale + mk);
        const float e2 = __expf(s2 * scale + mk);
        const float e3 = __expf(s3 * scale + mk);
        sp[0 * 64 + kl] = e0;
        sp[1 * 64 + kl] = e1;
        sp[2 * 64 + kl] = e2;
        sp[3 * 64 + kl] = e3;
        float l0 = e0, l1 = e1, l2 = e2, l3 = e3;
#pragma unroll
        for (int off = 32; off > 0; off >>= 1) {
            l0 += __shfl_xor(l0, off);
            l1 += __shfl_xor(l1, off);
            l2 += __shfl_xor(l2, off);
            l3 += __shfl_xor(l3, off);
        }
        if (t == 0) {
            float* pl = ws + WS_PL + ((size_t)(kx * 8 + hy)) * 4;
            pl[0] = l0; pl[1] = l1; pl[2] = l2; pl[3] = l3;
        }
    }
    __syncthreads();

    // ---- Phase B
    const int d = t & 127;
    const int kg = t >> 7;            // wave-uniform
    const int kb = k0 + kg * 16;
    const float* __restrict__ vp = past_value + (size_t)kb * D_DIM + d;
    const float* __restrict__ vlast =
        (kb + 15 == PAST_K) ? (kvn + D_DIM + d) : (vp + 15 * (size_t)D_DIM);

    float b0 = 0.f, b1 = 0.f, b2 = 0.f, b3 = 0.f;
#pragma unroll
    for (int kk = 0; kk < 15; ++kk) {
        const float v = vp[(size_t)kk * D_DIM];
        b0 += sp[0 * 64 + kg * 16 + kk] * v;
        b1 += sp[1 * 64 + kg * 16 + kk] * v;
        b2 += sp[2 * 64 + kg * 16 + kk] * v;
        b3 += sp[3 * 64 + kg * 16 + kk] * v;
    }
    {
        const float v = *vlast;
        b0 += sp[0 * 64 + kg * 16 + 15] * v;
        b1 += sp[1 * 64 + kg * 16 + 15] * v;
        b2 += sp[2 * 64 + kg * 16 + 15] * v;
        b3 += sp[3 * 64 + kg * 16 + 15] * v;
    }
    __syncthreads();   // phase-A red readers done
    red[(kg * 4 + 0) * 128 + d] = b0;
    red[(kg * 4 + 1) * 128 + d] = b1;
    red[(kg * 4 + 2) * 128 + d] = b2;
    red[(kg * 4 + 3) * 128 + d] = b3;
    __syncthreads();

    const int hh = t >> 7;
    const float s = red[(0 * 4 + hh) * 128 + d] + red[(1 * 4 + hh) * 128 + d] +
                    red[(2 * 4 + hh) * 128 + d] + red[(3 * 4 + hh) * 128 + d];
    ws[WS_PA + (size_t)kx * 4096 + (h0 + hh) * D_DIM + d] = s;  // coalesced
}

// ---------------------------------------------------------------- out_proj matvec (split-K=256); fused attn/l reduction
// grid: (4, 256), 256 thr. Rows e0 = by*16 (all within head h = by>>3).
__global__ void k_proj(const float* __restrict__ proj_w,
                       float* __restrict__ ws) {
    __shared__ float sred[16 * 16];   // [kg16][el]
    __shared__ float lpart[2];
    __shared__ float sa[16];          // normalized attn row chunk
    const int t = threadIdx.x;
    const int by = blockIdx.y;
    const int e0 = by * 16;
    const int h  = by >> 3;
    const int hy = h >> 2;
    const int hh = h & 3;

    // attn[e0..e0+16) = sum over 128 kx partials
    {
        const int el = t & 15;
        const int kg = t >> 4;        // 16 groups of 8 kx
        float ps = 0.f;
#pragma unroll
        for (int j = 0; j < 8; ++j)
            ps += ws[WS_PA + (size_t)(kg * 8 + j) * 4096 + e0 + el];
        sred[kg * 16 + el] = ps;
    }
    // l[h] = sum over 128 kx
    if (t < 128) {
        float lv = ws[WS_PL + ((size_t)(t * 8 + hy)) * 4 + hh];
#pragma unroll
        for (int off = 32; off > 0; off >>= 1) lv += __shfl_xor(lv, off);
        if ((t & 63) == 0) lpart[t >> 6] = lv;
    }
    __syncthreads();
    if (t < 16) {
        float asum = 0.f;
#pragma unroll
        for (int g = 0; g < 16; ++g) asum += sred[g * 16 + t];
        sa[t] = asum / (lpart[0] + lpart[1]);
    }
    __syncthreads();

    const int o = blockIdx.x * 1024 + t * 4;
    float ax = 0.f, ay = 0.f, az = 0.f, aw = 0.f;
#pragma unroll
    for (int i = 0; i < 16; ++i) {
        const float x = sa[i];  // LDS broadcast
        const float4 w = *reinterpret_cast<const float4*>(proj_w + (size_t)(e0 + i) * E_DIM + o);
        ax += x * w.x; ay += x * w.y; az += x * w.z; aw += x * w.w;
    }
    *reinterpret_cast<float4*>(ws + WS_PP + (size_t)by * 4096 + o) =
        make_float4(ax, ay, az, aw);
}

// ---------------------------------------------------------------- reduce proj partials (+bias) -> d_out
// grid: 64 blocks x 256 thr. Block: 64 outputs x 4 split-groups(64 splits).
__global__ void k_proj_reduce(const float* __restrict__ proj_b,
                              float* __restrict__ ws, float* __restrict__ out) {
    __shared__ float rr[256];
    const int t = threadIdx.x;
    const int ol = t & 63;
    const int sg = t >> 6;
    const int o = blockIdx.x * 64 + ol;
    float acc = 0.f;
#pragma unroll 8
    for (int s = sg * 64; s < sg * 64 + 64; ++s)
        acc += ws[WS_PP + (size_t)s * 4096 + o];
    rr[sg * 64 + ol] = acc;
    __syncthreads();
    if (t < 64) {
        const int oo = blockIdx.x * 64 + ol;
        out[oo] = rr[ol] + rr[64 + ol] + rr[128 + ol] + rr[192 + ol] + proj_b[oo];
    }
}

extern "C" void kernel_launch(void* const* d_in, const int* in_sizes, int n_in,
                              void* d_out, int out_size, void* d_ws, size_t ws_size,
                              hipStream_t stream) {
    const float* hs      = (const float*)d_in[0];
    const float* past_k  = (const float*)d_in[1];
    const float* past_v  = (const float*)d_in[2];
    const float* mask    = (const float*)d_in[3];
    const float* q_w     = (const float*)d_in[4];
    const float* q_b     = (const float*)d_in[5];
    const float* kv_w    = (const float*)d_in[6];
    const float* kv_b    = (const float*)d_in[7];
    const float* proj_w  = (const float*)d_in[8];
    const float* proj_b  = (const float*)d_in[9];
    float* out = (float*)d_out;
    float* ws  = (float*)d_ws;

    k_qkv        <<<dim3(5, 256), dim3(256), 0, stream>>>(hs, q_w, kv_w, ws);
    k_qkv_reduce <<<dim3(68),     dim3(256), 0, stream>>>(q_b, kv_b, ws, out);
    k_attn       <<<dim3(128, 8), dim3(512), 0, stream>>>(past_k, past_v, mask, ws);
    k_proj       <<<dim3(4, 256), dim3(256), 0, stream>>>(proj_w, ws);
    k_proj_reduce<<<dim3(64),     dim3(256), 0, stream>>>(proj_b, ws, out);
}

// Round 7
// 194.942 us; speedup vs baseline: 1.2213x; 1.0317x over previous
//
#include <hip/hip_runtime.h>
#include <math.h>

#define E_DIM 4096
#define H_NUM 32
#define D_DIM 128
#define PAST_K 8191
#define K_TOT 8192

// workspace layout (float offsets)
#define WS_QUERY 0                       // 4096
#define WS_KV    4096                    // 256 (key_new 0:128, value_new 128:256)
#define WS_PQ    4608                    // qkv partials: 256 splits x 4352
#define WS_PA    (WS_PQ + 256*4352)      // attn partials: 128 kx x 4096
#define WS_PL    (WS_PA + 128*4096)      // l partials: 128 kx x 4 hy x 8
#define WS_PP    (WS_PL + 4096)          // proj partials: 256 splits x 4096

// ---------------------------------------------------------------- q + kv matvec (split-K=256, partial stores)
// grid: (3, 256), 512 thr. bx<2 -> q cols [bx*2048,+2048); bx==2 -> kv (256 outs, 64 thr). 16 rows per by.
__global__ void __launch_bounds__(512, 2)
k_qkv(const float* __restrict__ hs,
      const float* __restrict__ q_w,
      const float* __restrict__ kv_w,
      float* __restrict__ ws) {
    const int t = threadIdx.x;
    const int e0 = blockIdx.y * 16;
    if (blockIdx.x < 2) {
        const int o = blockIdx.x * 2048 + t * 4;
        float ax = 0.f, ay = 0.f, az = 0.f, aw = 0.f;
#pragma unroll
        for (int i = 0; i < 16; ++i) {
            const int e = e0 + i;
            const float x = hs[e];
            const float4 w = *reinterpret_cast<const float4*>(q_w + (size_t)e * E_DIM + o);
            ax += x * w.x; ay += x * w.y; az += x * w.z; aw += x * w.w;
        }
        *reinterpret_cast<float4*>(ws + WS_PQ + (size_t)blockIdx.y * 4352 + o) =
            make_float4(ax, ay, az, aw);
    } else {
        if (t >= 64) return;
        const int o = t * 4;
        float ax = 0.f, ay = 0.f, az = 0.f, aw = 0.f;
#pragma unroll
        for (int i = 0; i < 16; ++i) {
            const int e = e0 + i;
            const float x = hs[e];
            const float4 w = *reinterpret_cast<const float4*>(kv_w + (size_t)e * 256 + o);
            ax += x * w.x; ay += x * w.y; az += x * w.z; aw += x * w.w;
        }
        *reinterpret_cast<float4*>(ws + WS_PQ + (size_t)blockIdx.y * 4352 + 4096 + o) =
            make_float4(ax, ay, az, aw);
    }
}

// ---------------------------------------------------------------- reduce qkv partials (+bias); also emits out[4096:4352]
// grid: 136 blocks x 256 thr. Block: 32 outputs x 8 split-groups(32 splits).
__global__ void __launch_bounds__(256, 4)
k_qkv_reduce(const float* __restrict__ q_b, const float* __restrict__ kv_b,
             float* __restrict__ ws, float* __restrict__ out) {
    __shared__ float rr[256];
    const int t = threadIdx.x;
    const int ol = t & 31;
    const int sg = t >> 5;
    const int o = blockIdx.x * 32 + ol;
    float acc = 0.f;
#pragma unroll 8
    for (int s = sg * 32; s < sg * 32 + 32; ++s)
        acc += ws[WS_PQ + (size_t)s * 4352 + o];
    rr[t] = acc;
    __syncthreads();
    if (t < 32) {
        float v = 0.f;
#pragma unroll
        for (int g = 0; g < 8; ++g) v += rr[g * 32 + t];
        const int oo = blockIdx.x * 32 + t;
        if (oo < 4096) {
            ws[WS_QUERY + oo] = v + q_b[oo];
        } else {
            const int i = oo - 4096;
            const float r = v + kv_b[i];
            ws[WS_KV + i] = r;
            out[oo] = r;  // key_perm / value_new outputs (out[4096:4352])
        }
    }
}

// ---------------------------------------------------------------- fused attention: scores -> exp -> PV partials
// grid: (128, 4) = 512 blocks, 512 thr. 64 k per bx, 8 heads per by. No atomics.
// Phase A: 64 k-lanes x 8 d-teams(16 d). Phase B: 128 d-lanes x 4 kg(16 k).
__global__ void __launch_bounds__(512, 2)
k_attn(const float* __restrict__ past_key,
       const float* __restrict__ past_value,
       const float* __restrict__ mask,
       float* __restrict__ ws) {
    __shared__ float sq[8 * 128];     // q tile (8 heads x 128 d), 4 KB
    __shared__ float sp[8 * 64];      // unnormalized probs, 2 KB
    __shared__ float red[3584];       // 14 KB (A: [7 teams][8 h][64 k]; B: [3 kg][8 h][128 d])
    const int t = threadIdx.x;
    const int hy = blockIdx.y;
    const int kx = blockIdx.x;
    const int h0 = hy * 8;
    const int k0 = kx * 64;
    const float* __restrict__ kvn = ws + WS_KV;

    sq[t]       = ws[WS_QUERY + h0 * D_DIM + t];
    sq[t + 512] = ws[WS_QUERY + h0 * D_DIM + t + 512];
    __syncthreads();

    // ---- Phase A
    const int kl = t & 63;
    const int team = t >> 6;          // wave-uniform
    const int d0 = team * 16;
    const int k = k0 + kl;
    const bool tailA = (k == PAST_K);
    const float* kp = tailA ? (kvn + d0) : (past_key + (size_t)d0 * PAST_K + k);
    const size_t kstr = tailA ? 1 : PAST_K;

    float acc[8];
#pragma unroll
    for (int h = 0; h < 8; ++h) acc[h] = 0.f;

#pragma unroll
    for (int i = 0; i < 16; i += 4) {
        const float v0 = kp[0];
        const float v1 = kp[kstr];
        const float v2 = kp[2 * kstr];
        const float v3 = kp[3 * kstr];
        kp += 4 * kstr;
#pragma unroll
        for (int h = 0; h < 8; ++h) {
            const float4 q = *reinterpret_cast<const float4*>(&sq[h * 128 + d0 + i]);
            acc[h] += q.x * v0 + q.y * v1 + q.z * v2 + q.w * v3;
        }
    }
    if (team != 0) {
#pragma unroll
        for (int h = 0; h < 8; ++h)
            red[((team - 1) * 8 + h) * 64 + kl] = acc[h];
    }
    __syncthreads();
    if (team == 0) {   // one full wave
        const float scale = 0.08838834764831845f;  // 1/sqrt(128)
        const float mk = mask[k];
        float l[8];
#pragma unroll
        for (int h = 0; h < 8; ++h) {
            float s = acc[h];
#pragma unroll
            for (int tm = 0; tm < 7; ++tm) s += red[(tm * 8 + h) * 64 + kl];
            const float e = __expf(s * scale + mk);
            sp[h * 64 + kl] = e;
            l[h] = e;
        }
#pragma unroll
        for (int h = 0; h < 8; ++h) {
#pragma unroll
            for (int off = 32; off > 0; off >>= 1) l[h] += __shfl_xor(l[h], off);
        }
        if (t == 0) {
            float* pl = ws + WS_PL + ((size_t)(kx * 4 + hy)) * 8;
#pragma unroll
            for (int h = 0; h < 8; ++h) pl[h] = l[h];
        }
    }
    __syncthreads();

    // ---- Phase B
    const int d = t & 127;
    const int kg = t >> 7;            // wave-uniform
    const int kb = k0 + kg * 16;
    const float* __restrict__ vp = past_value + (size_t)kb * D_DIM + d;
    const float* __restrict__ vlast =
        (kb + 15 == PAST_K) ? (kvn + D_DIM + d) : (vp + 15 * (size_t)D_DIM);

    float b[8];
#pragma unroll
    for (int h = 0; h < 8; ++h) b[h] = 0.f;

#pragma unroll
    for (int kk = 0; kk < 15; ++kk) {
        const float v = vp[(size_t)kk * D_DIM];
#pragma unroll
        for (int h = 0; h < 8; ++h) b[h] += sp[h * 64 + kg * 16 + kk] * v;
    }
    {
        const float v = *vlast;
#pragma unroll
        for (int h = 0; h < 8; ++h) b[h] += sp[h * 64 + kg * 16 + 15] * v;
    }
    __syncthreads();   // phase-A red readers done
    if (kg != 0) {
#pragma unroll
        for (int h = 0; h < 8; ++h)
            red[((kg - 1) * 8 + h) * 128 + d] = b[h];
    }
    __syncthreads();
    if (kg == 0) {
#pragma unroll
        for (int h = 0; h < 8; ++h) {
            float s = b[h] + red[(0 * 8 + h) * 128 + d] +
                      red[(1 * 8 + h) * 128 + d] + red[(2 * 8 + h) * 128 + d];
            ws[WS_PA + (size_t)kx * 4096 + (h0 + h) * D_DIM + d] = s;  // coalesced
        }
    }
}

// ---------------------------------------------------------------- out_proj matvec (split-K=256); fused attn/l reduction
// grid: (2, 256), 512 thr. Rows e0 = by*16 (all within head h = by>>3).
__global__ void __launch_bounds__(512, 2)
k_proj(const float* __restrict__ proj_w,
       float* __restrict__ ws) {
    __shared__ float sred[32 * 16];   // [kg32][el], 2 KB
    __shared__ float lpart[2];
    __shared__ float sa[16];          // normalized attn row chunk
    const int t = threadIdx.x;
    const int by = blockIdx.y;
    const int e0 = by * 16;
    const int h  = by >> 3;           // global head of these rows

    // attn[e0..e0+16) = sum over 128 kx partials (32 groups x 4 kx)
    {
        const int el = t & 15;
        const int kg = t >> 4;
        float ps = 0.f;
#pragma unroll
        for (int j = 0; j < 4; ++j)
            ps += ws[WS_PA + (size_t)(kg * 4 + j) * 4096 + e0 + el];
        sred[kg * 16 + el] = ps;
    }
    // l[h] = sum over 128 kx
    if (t < 128) {
        float lv = ws[WS_PL + (size_t)t * 32 + (h >> 3) * 8 + (h & 7)];
#pragma unroll
        for (int off = 32; off > 0; off >>= 1) lv += __shfl_xor(lv, off);
        if ((t & 63) == 0) lpart[t >> 6] = lv;
    }
    __syncthreads();
    if (t < 16) {
        float asum = 0.f;
#pragma unroll
        for (int g = 0; g < 32; ++g) asum += sred[g * 16 + t];
        sa[t] = asum / (lpart[0] + lpart[1]);
    }
    __syncthreads();

    const int o = blockIdx.x * 2048 + t * 4;
    float ax = 0.f, ay = 0.f, az = 0.f, aw = 0.f;
#pragma unroll
    for (int i = 0; i < 16; ++i) {
        const float x = sa[i];  // LDS broadcast
        const float4 w = *reinterpret_cast<const float4*>(proj_w + (size_t)(e0 + i) * E_DIM + o);
        ax += x * w.x; ay += x * w.y; az += x * w.z; aw += x * w.w;
    }
    *reinterpret_cast<float4*>(ws + WS_PP + (size_t)by * 4096 + o) =
        make_float4(ax, ay, az, aw);
}

// ---------------------------------------------------------------- reduce proj partials (+bias) -> d_out
// grid: 128 blocks x 256 thr. Block: 32 outputs x 8 split-groups(32 splits).
__global__ void __launch_bounds__(256, 4)
k_proj_reduce(const float* __restrict__ proj_b,
              float* __restrict__ ws, float* __restrict__ out) {
    __shared__ float rr[256];
    const int t = threadIdx.x;
    const int ol = t & 31;
    const int sg = t >> 5;
    const int o = blockIdx.x * 32 + ol;
    float acc = 0.f;
#pragma unroll 8
    for (int s = sg * 32; s < sg * 32 + 32; ++s)
        acc += ws[WS_PP + (size_t)s * 4096 + o];
    rr[t] = acc;
    __syncthreads();
    if (t < 32) {
        float v = 0.f;
#pragma unroll
        for (int g = 0; g < 8; ++g) v += rr[g * 32 + t];
        const int oo = blockIdx.x * 32 + t;
        out[oo] = v + proj_b[oo];
    }
}

extern "C" void kernel_launch(void* const* d_in, const int* in_sizes, int n_in,
                              void* d_out, int out_size, void* d_ws, size_t ws_size,
                              hipStream_t stream) {
    const float* hs      = (const float*)d_in[0];
    const float* past_k  = (const float*)d_in[1];
    const float* past_v  = (const float*)d_in[2];
    const float* mask    = (const float*)d_in[3];
    const float* q_w     = (const float*)d_in[4];
    const float* q_b     = (const float*)d_in[5];
    const float* kv_w    = (const float*)d_in[6];
    const float* kv_b    = (const float*)d_in[7];
    const float* proj_w  = (const float*)d_in[8];
    const float* proj_b  = (const float*)d_in[9];
    float* out = (float*)d_out;
    float* ws  = (float*)d_ws;

    k_qkv        <<<dim3(3, 256), dim3(512), 0, stream>>>(hs, q_w, kv_w, ws);
    k_qkv_reduce <<<dim3(136),    dim3(256), 0, stream>>>(q_b, kv_b, ws, out);
    k_attn       <<<dim3(128, 4), dim3(512), 0, stream>>>(past_k, past_v, mask, ws);
    k_proj       <<<dim3(2, 256), dim3(512), 0, stream>>>(proj_w, ws);
    k_proj_reduce<<<dim3(128),    dim3(256), 0, stream>>>(proj_b, ws, out);
}